// Round 5
// baseline (903.236 us; speedup 1.0000x reference)
//
#include <hip/hip_runtime.h>

#define BB 1024
#define TT 200
#define TP 224              // padded T (14 MFMA tiles)
#define BT 448              // din_fused block threads (7 waves)
#define NEGF (-2147483648.0f)

typedef unsigned short u16;
typedef __attribute__((ext_vector_type(8))) short bf16x8;
typedef __attribute__((ext_vector_type(4))) float f32x4;

__device__ __forceinline__ u16 f2bf(float f) {
  unsigned u = __float_as_uint(f);
  u += 0x7fff + ((u >> 16) & 1);
  return (u16)(u >> 16);
}
__device__ __forceinline__ float bf2f(u16 h) {
  return __uint_as_float(((unsigned)h) << 16);
}
__device__ __forceinline__ float fast_sigmoid(float z) {
  return __builtin_amdgcn_rcpf(1.f + __expf(-z));
}

// ---------------------------------------------------------------------------
// K0: fold + transpose LAU weights to bf16.
// comb = [cur,hist,cur-hist,cur*hist]@W1 == cur@(Wa+Wc) + hist@(Wb-Wc) + (cur*hist)@Wd
// WpT[n][k] (256x256): k<128 -> W1[128+k][n]-W1[256+k][n] ; k>=128 -> W1[384+k-128][n]
// Wq [k][j] (128x256) fp32: W1[k][j]+W1[256+k][j]
// W2T[n][k] (128x256): W2[k][n]
// ---------------------------------------------------------------------------
__global__ void prep_weights(const float* __restrict__ w1, const float* __restrict__ w2,
                             u16* __restrict__ WpT, float* __restrict__ Wq,
                             u16* __restrict__ W2T) {
  int i = blockIdx.x * 256 + threadIdx.x;
  if (i < 65536) {
    int n = i >> 8, k = i & 255;
    float v;
    if (k < 128) v = w1[(128 + k) * 256 + n] - w1[(256 + k) * 256 + n];
    else         v = w1[(384 + (k - 128)) * 256 + n];
    WpT[n * 256 + k] = f2bf(v);
  } else if (i < 98304) {
    int j = i - 65536;
    int k = j >> 8, jc = j & 255;
    Wq[j] = w1[k * 256 + jc] + w1[(256 + k) * 256 + jc];
  } else if (i < 131072) {
    int j = i - 98304;           // j = n*256 + k
    int n = j >> 8, k = j & 255;
    W2T[j] = f2bf(w2[k * 128 + n]);
  }
}

// ---------------------------------------------------------------------------
// K1: bias1p = lau_b1 + cur @ Wq  (fp32), cur gathered locally
// ---------------------------------------------------------------------------
__global__ __launch_bounds__(256) void prep_batch(
    const int* __restrict__ mid, const int* __restrict__ cat,
    const float* __restrict__ mat_table, const float* __restrict__ cat_table,
    const float* __restrict__ lau_b1, const float* __restrict__ Wq,
    float* __restrict__ bias1p) {
  int b = blockIdx.x, tid = threadIdx.x;
  __shared__ float curL[128];
  if (tid < 64)        curL[tid] = mat_table[(long)mid[b] * 64 + tid];
  else if (tid < 128)  curL[tid] = cat_table[(long)cat[b] * 64 + (tid - 64)];
  __syncthreads();
  float s = lau_b1[tid];
  for (int k = 0; k < 128; ++k) s += curL[k] * Wq[k * 256 + tid];
  bias1p[b * 256 + tid] = s;
}

// ---------------------------------------------------------------------------
// K2 (fully fused, one block per batch row b):
//   gather hist(200x128)->LDS bf16 ; comb product-half built on the fly from
//   per-lane cur fragments ; per 32-col chunk: gemm1 -> sigmoid -> per-wave
//   LDS scratch transpose (C-layout -> A-layout, wave-private, DS in-order)
//   -> gemm2 accumulate ; then w3 dot -> aw ; block softmax over T ; pooled
//   sums from LDS hist ; write xmlp[b] directly.  No Xh / AW global traffic.
// 7 waves, wave w owns m-tiles {2w, 2w+1} (rows 32w..32w+31 of padded 224).
// ---------------------------------------------------------------------------
__global__ __launch_bounds__(BT, 4) void din_fused(
    const int* __restrict__ uid, const int* __restrict__ mid,
    const int* __restrict__ cat,
    const int* __restrict__ hmid, const int* __restrict__ hcat,
    const int* __restrict__ mask,
    const float* __restrict__ user_table,
    const float* __restrict__ mat_table, const float* __restrict__ cat_table,
    const float* __restrict__ bias1p,
    const u16* __restrict__ WpT, const u16* __restrict__ W2T,
    const float* __restrict__ b2, const float* __restrict__ w3,
    const float* __restrict__ b3,
    float* __restrict__ xmlp) {
  __shared__ __align__(16) u16 histL[TP][136];        // 60928 B (+8 pad: 2-way free)
  __shared__ __align__(16) u16 scratch[7][16][40];    // 8960 B, per-wave transpose
  __shared__ __align__(16) float curL[128];
  __shared__ float biasL[256];
  __shared__ float b2L[128], w3L[128];
  __shared__ float awL[TP];

  int tid = threadIdx.x, wave = tid >> 6, l = tid & 63;
  int q = l >> 4, r16 = l & 15;
  int b = blockIdx.x;

  // ---- stage 0: small loads ----
  if (tid < 256) biasL[tid] = bias1p[b * 256 + tid];
  if (tid >= 256 && tid < 384) { b2L[tid - 256] = b2[tid - 256]; w3L[tid - 256] = w3[tid - 256]; }
  if (tid >= 384 && tid < 448) curL[tid - 384] = mat_table[(long)mid[b] * 64 + (tid - 384)];
  if (tid < 64)                curL[64 + tid]  = cat_table[(long)cat[b] * 64 + tid];
  float b3v = b3[0];
  // zero pad rows 200..223 (24 rows x 136 u16 = 1632 u32)
  for (int j = tid; j < 1632; j += BT)
    ((unsigned*)&histL[200][0])[j] = 0;

  // ---- gather: 200 rows x 32 float4 ----
  const int* hm = hmid + b * TT;
  const int* hc = hcat + b * TT;
  #pragma unroll 4
  for (int i = tid; i < 6400; i += BT) {
    int r = i >> 5, c4 = i & 31, e0 = c4 * 4;
    float4 hv;
    if (e0 < 64) hv = *(const float4*)(mat_table + (long)hm[r] * 64 + e0);
    else         hv = *(const float4*)(cat_table + (long)hc[r] * 64 + (e0 - 64));
    u16 hb[4] = {f2bf(hv.x), f2bf(hv.y), f2bf(hv.z), f2bf(hv.w)};
    *(ushort4*)(&histL[r][e0]) = *(ushort4*)hb;
  }
  __syncthreads();                                   // barrier 1

  // ---- per-wave gemm over its 2 m-tiles ----
  for (int mt = 0; mt < 2; ++mt) {
    int tile = wave * 2 + mt;                        // 0..13
    // A-fragments for all 8 k-slices: [0..3] = hist, [4..7] = hist*cur
    bf16x8 afr[8];
    #pragma unroll
    for (int k4 = 0; k4 < 4; ++k4) {
      bf16x8 h = *(const bf16x8*)(&histL[tile * 16 + r16][k4 * 32 + q * 8]);
      afr[k4] = h;
      float4 c0 = *(const float4*)(&curL[k4 * 32 + q * 8]);
      float4 c1 = *(const float4*)(&curL[k4 * 32 + q * 8 + 4]);
      bf16x8 pr;
      pr[0] = (short)f2bf(bf2f((u16)h[0]) * c0.x);
      pr[1] = (short)f2bf(bf2f((u16)h[1]) * c0.y);
      pr[2] = (short)f2bf(bf2f((u16)h[2]) * c0.z);
      pr[3] = (short)f2bf(bf2f((u16)h[3]) * c0.w);
      pr[4] = (short)f2bf(bf2f((u16)h[4]) * c1.x);
      pr[5] = (short)f2bf(bf2f((u16)h[5]) * c1.y);
      pr[6] = (short)f2bf(bf2f((u16)h[6]) * c1.z);
      pr[7] = (short)f2bf(bf2f((u16)h[7]) * c1.w);
      afr[4 + k4] = pr;
    }

    f32x4 acc2[8] = {};
    for (int nc = 0; nc < 8; ++nc) {
      // gemm1 chunk: cols [nc*32, nc*32+32)
      f32x4 acc1[2] = {};
      const u16* wpb = WpT + (nc * 32 + r16) * 256 + q * 8;
      bf16x8 bf0 = *(const bf16x8*)(wpb);
      bf16x8 bf1 = *(const bf16x8*)(wpb + 4096);
      #pragma unroll
      for (int ki = 0; ki < 8; ++ki) {
        bf16x8 b0 = bf0, b1 = bf1;
        if (ki < 7) {
          bf0 = *(const bf16x8*)(wpb + (ki + 1) * 32);
          bf1 = *(const bf16x8*)(wpb + 4096 + (ki + 1) * 32);
        }
        acc1[0] = __builtin_amdgcn_mfma_f32_16x16x32_bf16(afr[ki], b0, acc1[0], 0, 0, 0);
        acc1[1] = __builtin_amdgcn_mfma_f32_16x16x32_bf16(afr[ki], b1, acc1[1], 0, 0, 0);
      }
      // sigmoid + C->A transpose through wave-private scratch
      #pragma unroll
      for (int bn = 0; bn < 2; ++bn)
        #pragma unroll
        for (int r = 0; r < 4; ++r) {
          float z = acc1[bn][r] + biasL[nc * 32 + bn * 16 + r16];
          scratch[wave][q * 4 + r][bn * 16 + r16] = f2bf(fast_sigmoid(z));
        }
      __builtin_amdgcn_wave_barrier();   // wave-private LDS; DS is in-order per wave
      bf16x8 a2 = *(const bf16x8*)(&scratch[wave][r16][q * 8]);
      __builtin_amdgcn_wave_barrier();
      // gemm2 partial for k-chunk nc
      const u16* w2b = W2T + r16 * 256 + nc * 32 + q * 8;
      #pragma unroll
      for (int n2 = 0; n2 < 8; ++n2)
        acc2[n2] = __builtin_amdgcn_mfma_f32_16x16x32_bf16(
            a2, *(const bf16x8*)(w2b + n2 * 4096), acc2[n2], 0, 0, 0);
    }
    // aw epilogue for this tile: rp = sum_n w3[n]*sigmoid(acc2+b2)
    float rp[4] = {0.f, 0.f, 0.f, 0.f};
    #pragma unroll
    for (int n2 = 0; n2 < 8; ++n2) {
      float b2v = b2L[n2 * 16 + r16], w3v = w3L[n2 * 16 + r16];
      #pragma unroll
      for (int r = 0; r < 4; ++r)
        rp[r] += w3v * fast_sigmoid(acc2[n2][r] + b2v);
    }
    #pragma unroll
    for (int off = 1; off < 16; off <<= 1)
      #pragma unroll
      for (int r = 0; r < 4; ++r)
        rp[r] += __shfl_xor(rp[r], off, 16);
    if (r16 == 0)
      #pragma unroll
      for (int r = 0; r < 4; ++r)
        awL[tile * 16 + q * 4 + r] = rp[r] + b3v;
  }
  __syncthreads();                                   // barrier 2: gemms + aw done

  // ---- softmax over T + pooling (aliases scratch: all gemm use finished) ----
  float* scL   = (float*)&scratch[0][0][0];          // 224
  float* mkL   = scL + 224;                          // 224
  float* redA  = scL + 448;                          // 256
  float* redB  = scL + 704;                          // 256
  float* poolL = scL + 960;                          // 3*128
  float* poolH = scL + 1344;                         // 3*128  (total 6912 B <= 8960)

  int mk = 0; float masked = NEGF;
  if (tid < TT) { mk = mask[b * TT + tid]; masked = mk ? awL[tid] : NEGF; }
  if (tid < 256) redA[tid] = masked;
  __syncthreads();
  for (int s = 128; s > 0; s >>= 1) {
    if (tid < s) redA[tid] = fmaxf(redA[tid], redA[tid + s]);
    __syncthreads();
  }
  float mx = redA[0];
  __syncthreads();
  float ev = (tid < TT) ? __expf(masked - mx) : 0.f;
  if (tid < 256) { redA[tid] = ev; redB[tid] = (tid < TT) ? (float)mk : 0.f; }
  __syncthreads();
  for (int s = 128; s > 0; s >>= 1) {
    if (tid < s) { redA[tid] += redA[tid + s]; redB[tid] += redB[tid + s]; }
    __syncthreads();
  }
  float rden = __builtin_amdgcn_rcpf(redA[0]);
  float cnt  = redB[0];
  __syncthreads();
  if (tid < TT) { scL[tid] = ev * rden * (float)mk; mkL[tid] = (float)mk; }
  __syncthreads();

  if (tid < 384) {
    int c = tid & 127, p = tid >> 7;                 // p in 0..2
    float sL = 0.f, sH = 0.f;
    for (int t = p; t < TT; t += 3) {
      float hv = bf2f(histL[t][c]);
      sL += scL[t] * hv;
      sH += mkL[t] * hv;
    }
    poolL[p * 128 + c] = sL;
    poolH[p * 128 + c] = sH;
  }
  __syncthreads();

  float rcnt = __builtin_amdgcn_rcpf(cnt);
  if (tid < 64) {
    xmlp[b * 448 + tid] = user_table[(long)uid[b] * 64 + tid];
  } else if (tid < 192) {
    xmlp[b * 448 + tid] = curL[tid - 64];
  } else if (tid < 320) {
    int c = tid - 192;
    xmlp[b * 448 + tid] = poolL[c] + poolL[128 + c] + poolL[256 + c];
  } else {
    int c = tid - 320;
    xmlp[b * 448 + tid] = (poolH[c] + poolH[128 + c] + poolH[256 + c]) * rcnt;
  }
}

// ---------------------------------------------------------------------------
// K4: column partial sums/sumsq of X[1024, cols] into [16][cols] chunks
// ---------------------------------------------------------------------------
__global__ __launch_bounds__(256) void colstats(const float* __restrict__ X, int cols,
                                                float* __restrict__ psum,
                                                float* __restrict__ psq) {
  int cg = blockIdx.x, rc = blockIdx.y;
  int c = threadIdx.x & 63, ty = threadIdx.x >> 6;
  int col = cg * 64 + c;
  float s = 0.f, ss = 0.f;
  for (int i = 0; i < 16; ++i) {
    int r = rc * 64 + ty + i * 4;
    float v = X[(long)r * cols + col];
    s += v; ss += v * v;
  }
  __shared__ float s1[256], s2[256];
  s1[threadIdx.x] = s; s2[threadIdx.x] = ss;
  __syncthreads();
  if (ty == 0) {
    s  = s1[c] + s1[c + 64] + s1[c + 128] + s1[c + 192];
    ss = s2[c] + s2[c + 64] + s2[c + 128] + s2[c + 192];
    psum[rc * cols + col] = s;
    psq [rc * cols + col] = ss;
  }
}

// ---------------------------------------------------------------------------
// K5: C[1024,N] = (act(bn(A)) @ W) + bias, plus per-M-tile column stats of C.
// ---------------------------------------------------------------------------
template <bool LEAKY>
__global__ __launch_bounds__(256) void gemm_bn(
    const float* __restrict__ A, int K,
    const float* __restrict__ psumA, const float* __restrict__ psqA,
    const float* __restrict__ g, const float* __restrict__ bta,
    const float* __restrict__ W, const float* __restrict__ bias, int N,
    float* __restrict__ C, float* __restrict__ psumC, float* __restrict__ psqC) {
  __shared__ float As[16][65], Bs[16][65];
  __shared__ float scK[512], shK[512];
  __shared__ float colS[16][64], colQ[16][64];
  int tid = threadIdx.x;
  for (int j = tid; j < K; j += 256) {
    float s = 0.f, ss = 0.f;
    for (int rc = 0; rc < 16; ++rc) { s += psumA[rc * K + j]; ss += psqA[rc * K + j]; }
    float mu = s * (1.f / 1024.f), var = ss * (1.f / 1024.f) - mu * mu;
    float scv = rsqrtf(var + 1e-5f) * g[j];
    scK[j] = scv; shK[j] = bta[j] - mu * scv;
  }
  __syncthreads();
  int m0 = blockIdx.x * 64, n0 = blockIdx.y * 64;
  int tx = tid & 15, ty = tid >> 4;
  float acc[4][4] = {};
  for (int k0 = 0; k0 < K; k0 += 16) {
    __syncthreads();
    for (int i = tid; i < 1024; i += 256) {
      int m = i >> 4, k = i & 15;
      float v = A[(long)(m0 + m) * K + k0 + k] * scK[k0 + k] + shK[k0 + k];
      if (LEAKY) v = v > 0.f ? v : 0.1f * v;
      As[k][m] = v;
    }
    for (int i = tid; i < 1024; i += 256) {
      int k = i >> 6, n = i & 63;
      Bs[k][n] = W[(long)(k0 + k) * N + n0 + n];
    }
    __syncthreads();
    for (int k = 0; k < 16; ++k) {
      float a[4], bq[4];
      for (int ii = 0; ii < 4; ++ii) a[ii]  = As[k][ty * 4 + ii];
      for (int jj = 0; jj < 4; ++jj) bq[jj] = Bs[k][tx * 4 + jj];
      for (int ii = 0; ii < 4; ++ii)
        for (int jj = 0; jj < 4; ++jj) acc[ii][jj] += a[ii] * bq[jj];
    }
  }
  float cs4[4], cq4[4];
  for (int jj = 0; jj < 4; ++jj) {
    int n = n0 + tx * 4 + jj;
    float bv = bias[n];
    float cs = 0.f, cq = 0.f;
    for (int ii = 0; ii < 4; ++ii) {
      float val = acc[ii][jj] + bv;
      C[(long)(m0 + ty * 4 + ii) * N + n] = val;
      cs += val; cq += val * val;
    }
    cs4[jj] = cs; cq4[jj] = cq;
  }
  __syncthreads();
  for (int jj = 0; jj < 4; ++jj) {
    colS[ty][tx * 4 + jj] = cs4[jj];
    colQ[ty][tx * 4 + jj] = cq4[jj];
  }
  __syncthreads();
  if (tid < 64) {
    float s = 0.f, ss = 0.f;
    for (int t = 0; t < 16; ++t) { s += colS[t][tid]; ss += colQ[t][tid]; }
    psumC[blockIdx.x * N + n0 + tid] = s;
    psqC [blockIdx.x * N + n0 + tid] = ss;
  }
}

// ---------------------------------------------------------------------------
// K6: out = leaky(bn2(y2)) @ W3[256,2] + b3.  grid 16 x 256.
// ---------------------------------------------------------------------------
__global__ __launch_bounds__(256) void final_out(
    const float* __restrict__ y2,
    const float* __restrict__ psum2, const float* __restrict__ psq2,
    const float* __restrict__ g, const float* __restrict__ bta,
    const float* __restrict__ w3, const float* __restrict__ b3,
    float* __restrict__ out) {
  __shared__ float sc2[256], sh2[256];
  __shared__ float p0[256], p1[256];
  int tid = threadIdx.x;
  {
    float s = 0.f, ss = 0.f;
    for (int rc = 0; rc < 16; ++rc) { s += psum2[rc * 256 + tid]; ss += psq2[rc * 256 + tid]; }
    float mu = s * (1.f / 1024.f), var = ss * (1.f / 1024.f) - mu * mu;
    float scv = rsqrtf(var + 1e-5f) * g[tid];
    sc2[tid] = scv; sh2[tid] = bta[tid] - mu * scv;
  }
  __syncthreads();
  int row = blockIdx.x * 64 + (tid >> 2), qq = tid & 3;
  const float* yr = y2 + (long)row * 256;
  float a0 = 0.f, a1 = 0.f;
  for (int k = qq * 64; k < qq * 64 + 64; ++k) {
    float v = yr[k] * sc2[k] + sh2[k];
    v = v > 0.f ? v : 0.1f * v;
    a0 += v * w3[2 * k];
    a1 += v * w3[2 * k + 1];
  }
  p0[tid] = a0; p1[tid] = a1;
  __syncthreads();
  if (qq == 0) {
    out[row * 2 + 0] = p0[tid] + p0[tid + 1] + p0[tid + 2] + p0[tid + 3] + b3[0];
    out[row * 2 + 1] = p1[tid] + p1[tid + 1] + p1[tid + 2] + p1[tid + 3] + b3[1];
  }
}

// ---------------------------------------------------------------------------

extern "C" void kernel_launch(void* const* d_in, const int* in_sizes, int n_in,
                              void* d_out, int out_size, void* d_ws, size_t ws_size,
                              hipStream_t stream) {
  const int* uid  = (const int*)d_in[0];
  const int* mid  = (const int*)d_in[1];
  const int* cat  = (const int*)d_in[2];
  const int* hmid = (const int*)d_in[3];
  const int* hcat = (const int*)d_in[4];
  const int* mask = (const int*)d_in[5];
  const float* user_table = (const float*)d_in[6];
  const float* mat_table  = (const float*)d_in[7];
  const float* cat_table  = (const float*)d_in[8];
  const float* lau_w1 = (const float*)d_in[9];
  const float* lau_b1 = (const float*)d_in[10];
  const float* lau_w2 = (const float*)d_in[11];
  const float* lau_b2 = (const float*)d_in[12];
  const float* lau_w3 = (const float*)d_in[13];
  const float* lau_b3 = (const float*)d_in[14];
  const float* bn0_g = (const float*)d_in[15];
  const float* bn0_b = (const float*)d_in[16];
  const float* mlp_w1 = (const float*)d_in[17];
  const float* mlp_b1 = (const float*)d_in[18];
  const float* bn1_g = (const float*)d_in[19];
  const float* bn1_b = (const float*)d_in[20];
  const float* mlp_w2 = (const float*)d_in[21];
  const float* mlp_b2 = (const float*)d_in[22];
  const float* bn2_g = (const float*)d_in[23];
  const float* bn2_b = (const float*)d_in[24];
  const float* mlp_w3 = (const float*)d_in[25];
  const float* mlp_b3 = (const float*)d_in[26];
  float* out = (float*)d_out;

  char* w = (char*)d_ws;
  size_t off = 0;
  auto take = [&](size_t bytes) { size_t o = off; off += (bytes + 255) & ~(size_t)255; return o; };
  float* bias1p = (float*)(w + take((size_t)BB * 256 * 4));
  float* xmlp   = (float*)(w + take((size_t)BB * 448 * 4));
  float* y1     = (float*)(w + take((size_t)BB * 512 * 4));
  float* y2     = (float*)(w + take((size_t)BB * 256 * 4));
  u16*   WpT    = (u16*)  (w + take(256 * 256 * 2));
  float* Wq     = (float*)(w + take(128 * 256 * 4));
  u16*   W2T    = (u16*)  (w + take(128 * 256 * 2));
  float* psum0  = (float*)(w + take(16 * 448 * 4));
  float* psq0   = (float*)(w + take(16 * 448 * 4));
  float* psum1  = (float*)(w + take(16 * 512 * 4));
  float* psq1   = (float*)(w + take(16 * 512 * 4));
  float* psum2  = (float*)(w + take(16 * 256 * 4));
  float* psq2   = (float*)(w + take(16 * 256 * 4));

  prep_weights<<<512, 256, 0, stream>>>(lau_w1, lau_w2, WpT, Wq, W2T);
  prep_batch<<<BB, 256, 0, stream>>>(mid, cat, mat_table, cat_table, lau_b1, Wq, bias1p);
  din_fused<<<BB, BT, 0, stream>>>(uid, mid, cat, hmid, hcat, mask,
                                   user_table, mat_table, cat_table,
                                   bias1p, WpT, W2T, lau_b2, lau_w3, lau_b3, xmlp);
  {
    dim3 g(448 / 64, 16);
    colstats<<<g, 256, 0, stream>>>(xmlp, 448, psum0, psq0);
  }
  {
    dim3 g(16, 512 / 64);
    gemm_bn<false><<<g, 256, 0, stream>>>(xmlp, 448, psum0, psq0, bn0_g, bn0_b,
                                          mlp_w1, mlp_b1, 512, y1, psum1, psq1);
  }
  {
    dim3 g(16, 256 / 64);
    gemm_bn<true><<<g, 256, 0, stream>>>(y1, 512, psum1, psq1, bn1_g, bn1_b,
                                         mlp_w2, mlp_b2, 256, y2, psum2, psq2);
  }
  final_out<<<16, 256, 0, stream>>>(y2, psum2, psq2, bn2_g, bn2_b, mlp_w3, mlp_b3, out);
}